// Round 1
// baseline (2384.834 us; speedup 1.0000x reference)
//
#include <hip/hip_runtime.h>
#include <hip/hip_bf16.h>
#include <math.h>

// ---------------- problem constants (match reference) ----------------
constexpr int N_NODES  = 20000;
constexpr int E_EDGES  = 320000;
constexpr int G_GRAPHS = 64;
constexpr int F_IN     = 128;
constexpr int H_DIM    = 256;   // 8 heads x 32
constexpr int LAYERS   = 8;
constexpr int OUT_DIM  = 128;
constexpr float SCALE_ATT = 0.17677669529663687f; // 1/sqrt(32)

// ---------------- CSR build ----------------
__global__ void count_kernel(const int* __restrict__ dst, int E, int* __restrict__ counts) {
    int i = blockIdx.x * blockDim.x + threadIdx.x;
    if (i < E) atomicAdd(&counts[dst[i]], 1);
}

__global__ __launch_bounds__(1024) void scan_kernel(const int* __restrict__ counts,
                                                    int* __restrict__ offsets, int n) {
    __shared__ int buf[1024];
    __shared__ int carry;
    const int tid = threadIdx.x;
    if (tid == 0) { carry = 0; offsets[0] = 0; }
    __syncthreads();
    for (int base = 0; base < n; base += 1024) {
        int i = base + tid;
        int v = (i < n) ? counts[i] : 0;
        buf[tid] = v;
        __syncthreads();
        #pragma unroll
        for (int off = 1; off < 1024; off <<= 1) {
            int x = (tid >= off) ? buf[tid - off] : 0;
            __syncthreads();
            buf[tid] += x;
            __syncthreads();
        }
        if (i < n) offsets[i + 1] = carry + buf[tid];
        __syncthreads();
        if (tid == 0) carry += buf[1023];
        __syncthreads();
    }
}

__global__ void scatter_kernel(const int* __restrict__ src, const int* __restrict__ dst, int E,
                               const int* __restrict__ offsets, int* __restrict__ cursor,
                               int* __restrict__ esrc) {
    int i = blockIdx.x * blockDim.x + threadIdx.x;
    if (i < E) {
        int d = dst[i];
        int pos = atomicAdd(&cursor[d], 1);
        esrc[offsets[d] + pos] = src[i];
    }
}

// ---------------- fp32 tiled GEMM with bias ----------------
// C[r, z*256 + c] = A[r,:K] @ B_z[:K, c] + bias_z[c]; tile 64x64, 256 thr, 4x4/thread
struct GemmW { const float* B[4]; const float* bias[4]; };

__global__ __launch_bounds__(256) void gemm_bias(const float* __restrict__ A, int M, int K,
                                                 GemmW w, float* __restrict__ C, int ldc) {
    const int z = blockIdx.z;
    const float* __restrict__ B    = w.B[z];
    const float* __restrict__ bias = w.bias[z];
    const int row0 = blockIdx.x * 64;
    const int col0 = blockIdx.y * 64;   // within this weight's 256 cols

    __shared__ float As[16 * 68];  // As[kk][r]
    __shared__ float Bs[16 * 68];  // Bs[kk][c]

    const int t  = threadIdx.x;
    const int tr = t >> 4, tc = t & 15;
    const int ar = t >> 2;            // 0..63   A row within tile
    const int aq = (t & 3) * 4;       // k quad
    const int bk = t >> 4;            // 0..15   B k within tile
    const int bc = (t & 15) * 4;      // col quad

    float acc[4][4] = {};

    for (int k0 = 0; k0 < K; k0 += 16) {
        float4 av = make_float4(0.f, 0.f, 0.f, 0.f);
        int arow = row0 + ar;
        if (arow < M)
            av = *reinterpret_cast<const float4*>(A + (size_t)arow * K + k0 + aq);
        As[(aq + 0) * 68 + ar] = av.x;
        As[(aq + 1) * 68 + ar] = av.y;
        As[(aq + 2) * 68 + ar] = av.z;
        As[(aq + 3) * 68 + ar] = av.w;

        float4 bv = *reinterpret_cast<const float4*>(B + (size_t)(k0 + bk) * 256 + col0 + bc);
        *reinterpret_cast<float4*>(&Bs[bk * 68 + bc]) = bv;
        __syncthreads();

        #pragma unroll
        for (int kk = 0; kk < 16; ++kk) {
            float4 a = *reinterpret_cast<const float4*>(&As[kk * 68 + tr * 4]);
            float4 b = *reinterpret_cast<const float4*>(&Bs[kk * 68 + tc * 4]);
            float aa[4] = {a.x, a.y, a.z, a.w};
            float bb[4] = {b.x, b.y, b.z, b.w};
            #pragma unroll
            for (int i = 0; i < 4; ++i)
                #pragma unroll
                for (int j = 0; j < 4; ++j)
                    acc[i][j] += aa[i] * bb[j];
        }
        __syncthreads();
    }

    #pragma unroll
    for (int i = 0; i < 4; ++i) {
        int r = row0 + tr * 4 + i;
        if (r >= M) continue;
        #pragma unroll
        for (int j = 0; j < 4; ++j) {
            int c = col0 + tc * 4 + j;   // 0..255 within weight
            C[(size_t)r * ldc + z * 256 + c] = acc[i][j] + bias[c];
        }
    }
}

// ---------------- fused per-node: attention + beta gate + LN + ReLU ----------------
// qkvs layout per node: [q(256) | k(256) | v(256) | s(256)]
__global__ __launch_bounds__(256) void node_attn_kernel(
        const float* __restrict__ qkvs, const int* __restrict__ offsets,
        const int* __restrict__ esrc, const float* __restrict__ Wbeta,
        const float* __restrict__ ln_g, const float* __restrict__ ln_b,
        float* __restrict__ h_out) {
    const int n = blockIdx.x;
    const int t = threadIdx.x;       // channel = head*32 + c
    __shared__ int   s_src[256];
    __shared__ float red[8];
    __shared__ float s_beta;

    const float q = qkvs[(size_t)n * 1024 + t];

    float m = -1e30f, ssum = 0.f, acc = 0.f;
    const int rs = offsets[n], re = offsets[n + 1];

    for (int base = rs; base < re; base += 256) {
        int cnt = min(re - base, 256);
        if (t < cnt) s_src[t] = esrc[base + t];
        __syncthreads();
        for (int j = 0; j < cnt; ++j) {
            const int sidx = s_src[j];
            const float* row = qkvs + (size_t)sidx * 1024;
            float p = q * row[256 + t];
            #pragma unroll
            for (int o = 16; o >= 1; o >>= 1) p += __shfl_xor(p, o, 32);
            float alpha = p * SCALE_ATT;
            float vv = row[512 + t];
            float mnew = fmaxf(m, alpha);
            float scale = __expf(m - mnew);      // 0 when m = -1e30 (underflow)
            float e = __expf(alpha - mnew);
            ssum = ssum * scale + e;
            acc  = acc  * scale + e * vv;
            m = mnew;
        }
        __syncthreads();
    }

    const float out = acc / (ssum + 1e-16f);
    const float xr  = qkvs[(size_t)n * 1024 + 768 + t];

    // beta = sigmoid(sum_c out*(Wb[c]+Wb[512+c]) + xr*(Wb[256+c]-Wb[512+c]))
    float bl = out * (Wbeta[t] + Wbeta[512 + t]) + xr * (Wbeta[256 + t] - Wbeta[512 + t]);
    #pragma unroll
    for (int o = 32; o >= 1; o >>= 1) bl += __shfl_xor(bl, o, 64);
    const int wave = t >> 6;
    if ((t & 63) == 0) red[wave] = bl;
    __syncthreads();
    if (t == 0) {
        float v = red[0] + red[1] + red[2] + red[3];
        s_beta = 1.f / (1.f + __expf(-v));
    }
    __syncthreads();
    const float beta = s_beta;
    const float hn = beta * xr + (1.f - beta) * out;

    // layernorm over 256 channels (two-pass for accuracy)
    float r1 = hn;
    #pragma unroll
    for (int o = 32; o >= 1; o >>= 1) r1 += __shfl_xor(r1, o, 64);
    if ((t & 63) == 0) red[4 + wave] = r1;
    __syncthreads();
    const float mu = (red[4] + red[5] + red[6] + red[7]) * (1.f / 256.f);
    const float d = hn - mu;
    float r2 = d * d;
    #pragma unroll
    for (int o = 32; o >= 1; o >>= 1) r2 += __shfl_xor(r2, o, 64);
    if ((t & 63) == 0) red[wave] = r2;
    __syncthreads();
    const float var = (red[0] + red[1] + red[2] + red[3]) * (1.f / 256.f);

    float y = d * rsqrtf(var + 1e-5f) * ln_g[t] + ln_b[t];
    y = fmaxf(y, 0.f);
    h_out[(size_t)n * 256 + t] = y;
}

// ---------------- mean pool (batch is sorted) ----------------
__global__ __launch_bounds__(256) void pool_kernel(const float* __restrict__ h,
                                                   const int* __restrict__ batch, int Nn,
                                                   float* __restrict__ sums,
                                                   float* __restrict__ cnt) {
    const int start = blockIdx.x * 256;
    const int end = min(start + 256, Nn);
    if (start >= end) return;
    const int t = threadIdx.x;
    int cur = batch[start];
    float run = 0.f;
    int c = 0;
    for (int n = start; n < end; ++n) {
        int g = batch[n];
        if (g != cur) {
            atomicAdd(&sums[(size_t)cur * 256 + t], run);
            if (t == 0) atomicAdd(&cnt[cur], (float)c);
            run = 0.f; c = 0; cur = g;
        }
        run += h[(size_t)n * 256 + t];
        ++c;
    }
    atomicAdd(&sums[(size_t)cur * 256 + t], run);
    if (t == 0) atomicAdd(&cnt[cur], (float)c);
}

// ---------------- final projection: pooled @ W_final + b_final ----------------
__global__ __launch_bounds__(128) void final_kernel(const float* __restrict__ sums,
                                                    const float* __restrict__ cnt,
                                                    const float* __restrict__ Wf,
                                                    const float* __restrict__ bf,
                                                    float* __restrict__ out) {
    const int g = blockIdx.x;
    const int t = threadIdx.x;
    __shared__ float p[256];
    const float c = fmaxf(cnt[g], 1.f);
    for (int i = t; i < 256; i += 128) p[i] = sums[(size_t)g * 256 + i] / c;
    __syncthreads();
    float acc = bf[t];
    #pragma unroll 4
    for (int k = 0; k < 256; ++k) acc += p[k] * Wf[k * 128 + t];
    out[(size_t)g * 128 + t] = acc;
}

// ---------------- launcher ----------------
extern "C" void kernel_launch(void* const* d_in, const int* in_sizes, int n_in,
                              void* d_out, int out_size, void* d_ws, size_t ws_size,
                              hipStream_t stream) {
    const float* x       = (const float*)d_in[0];
    const int*   eidx    = (const int*)  d_in[1];
    const int*   batch   = (const int*)  d_in[2];
    const float* W_init  = (const float*)d_in[3];
    const float* b_init  = (const float*)d_in[4];
    const float* Wq      = (const float*)d_in[5];
    const float* bq      = (const float*)d_in[6];
    const float* Wk      = (const float*)d_in[7];
    const float* bk      = (const float*)d_in[8];
    const float* Wv      = (const float*)d_in[9];
    const float* bv      = (const float*)d_in[10];
    const float* Ws      = (const float*)d_in[11];
    const float* bs      = (const float*)d_in[12];
    const float* Wbeta   = (const float*)d_in[13];
    const float* ln_g    = (const float*)d_in[14];
    const float* ln_b    = (const float*)d_in[15];
    const float* W_final = (const float*)d_in[16];
    const float* b_final = (const float*)d_in[17];

    const int* e_src = eidx;             // edge_index[0]
    const int* e_dst = eidx + E_EDGES;   // edge_index[1]

    // workspace layout
    float* h       = (float*)d_ws;                   // N*256
    float* qkvs    = h + (size_t)N_NODES * 256;      // N*1024
    int*   counts  = (int*)(qkvs + (size_t)N_NODES * 1024);  // N
    int*   offsets = counts + N_NODES;               // N+1
    int*   cursor  = offsets + N_NODES + 1;          // N
    int*   esrc    = cursor + N_NODES;               // E
    float* sums    = (float*)(esrc + E_EDGES);       // G*256
    float* cnt     = sums + (size_t)G_GRAPHS * 256;  // G

    // zero what we accumulate into
    hipMemsetAsync(counts, 0, sizeof(int) * N_NODES, stream);
    hipMemsetAsync(cursor, 0, sizeof(int) * N_NODES, stream);
    hipMemsetAsync(sums, 0, sizeof(float) * G_GRAPHS * 256, stream);
    hipMemsetAsync(cnt, 0, sizeof(float) * G_GRAPHS, stream);

    // CSR by dst
    count_kernel<<<(E_EDGES + 255) / 256, 256, 0, stream>>>(e_dst, E_EDGES, counts);
    scan_kernel<<<1, 1024, 0, stream>>>(counts, offsets, N_NODES);
    scatter_kernel<<<(E_EDGES + 255) / 256, 256, 0, stream>>>(e_src, e_dst, E_EDGES,
                                                              offsets, cursor, esrc);

    const int rowTiles = (N_NODES + 63) / 64;

    // h0 = x @ W_init + b_init
    {
        GemmW w{};
        w.B[0] = W_init; w.bias[0] = b_init;
        dim3 grid(rowTiles, 4, 1);
        gemm_bias<<<grid, 256, 0, stream>>>(x, N_NODES, F_IN, w, h, 256);
    }

    for (int l = 0; l < LAYERS; ++l) {
        GemmW w{};
        w.B[0] = Wq + (size_t)l * 256 * 256; w.bias[0] = bq + (size_t)l * 256;
        w.B[1] = Wk + (size_t)l * 256 * 256; w.bias[1] = bk + (size_t)l * 256;
        w.B[2] = Wv + (size_t)l * 256 * 256; w.bias[2] = bv + (size_t)l * 256;
        w.B[3] = Ws + (size_t)l * 256 * 256; w.bias[3] = bs + (size_t)l * 256;
        dim3 grid(rowTiles, 4, 4);
        gemm_bias<<<grid, 256, 0, stream>>>(h, N_NODES, H_DIM, w, qkvs, 1024);

        node_attn_kernel<<<N_NODES, 256, 0, stream>>>(
            qkvs, offsets, esrc,
            Wbeta + (size_t)l * 768,
            ln_g + (size_t)l * 256, ln_b + (size_t)l * 256, h);
    }

    pool_kernel<<<(N_NODES + 255) / 256, 256, 0, stream>>>(h, batch, N_NODES, sums, cnt);
    final_kernel<<<G_GRAPHS, 128, 0, stream>>>(sums, cnt, W_final, b_final, (float*)d_out);
}

// Round 2
// 1777.445 us; speedup vs baseline: 1.3417x; 1.3417x over previous
//
#include <hip/hip_runtime.h>
#include <hip/hip_bf16.h>
#include <math.h>

// ---------------- problem constants ----------------
constexpr int N_NODES  = 20000;
constexpr int M_PAD    = 20096;   // 157 * 128 row tiles
constexpr int E_EDGES  = 320000;
constexpr int G_GRAPHS = 64;
constexpr int F_IN     = 128;
constexpr int H_DIM    = 256;
constexpr int LAYERS   = 8;
constexpr float SCALE_ATT = 0.17677669529663687f; // 1/sqrt(32)

typedef __attribute__((ext_vector_type(8))) short bf16x8;
typedef __attribute__((ext_vector_type(4))) float f32x4;
typedef unsigned int u32;

__device__ static inline void gload_lds16(void* lds, const void* g) {
    __builtin_amdgcn_global_load_lds((const __attribute__((address_space(1))) u32*)g,
                                     (__attribute__((address_space(3))) u32*)lds, 16, 0, 0);
}

// ---------------- CSR build ----------------
__global__ void count_kernel(const int* __restrict__ dst, int E, int* __restrict__ counts) {
    int i = blockIdx.x * blockDim.x + threadIdx.x;
    if (i < E) atomicAdd(&counts[dst[i]], 1);
}

__global__ __launch_bounds__(1024) void scan_kernel(const int* __restrict__ counts,
                                                    int* __restrict__ offsets, int n) {
    __shared__ int buf[1024];
    __shared__ int carry;
    const int tid = threadIdx.x;
    if (tid == 0) { carry = 0; offsets[0] = 0; }
    __syncthreads();
    for (int base = 0; base < n; base += 1024) {
        int i = base + tid;
        int v = (i < n) ? counts[i] : 0;
        buf[tid] = v;
        __syncthreads();
        #pragma unroll
        for (int off = 1; off < 1024; off <<= 1) {
            int x = (tid >= off) ? buf[tid - off] : 0;
            __syncthreads();
            buf[tid] += x;
            __syncthreads();
        }
        if (i < n) offsets[i + 1] = carry + buf[tid];
        __syncthreads();
        if (tid == 0) carry += buf[1023];
        __syncthreads();
    }
}

__global__ void scatter_kernel(const int* __restrict__ src, const int* __restrict__ dst, int E,
                               const int* __restrict__ offsets, int* __restrict__ cursor,
                               int* __restrict__ esrc) {
    int i = blockIdx.x * blockDim.x + threadIdx.x;
    if (i < E) {
        int d = dst[i];
        int pos = atomicAdd(&cursor[d], 1);
        esrc[offsets[d] + pos] = src[i];
    }
}

// ---------------- weight transpose + hi/lo bf16 split ----------------
// Wt[l*1024 + z*256 + n][k] = W_z[l][k][n]
__global__ __launch_bounds__(256) void wt_layers(
        const float* __restrict__ Wq, const float* __restrict__ Wk,
        const float* __restrict__ Wv, const float* __restrict__ Ws,
        __hip_bfloat16* __restrict__ Whi, __hip_bfloat16* __restrict__ Wlo) {
    const int l = blockIdx.z, z = blockIdx.y;
    const int tk = (blockIdx.x & 7) * 32;
    const int tn = (blockIdx.x >> 3) * 32;
    const float* src = (z == 0 ? Wq : z == 1 ? Wk : z == 2 ? Wv : Ws) + (size_t)l * 65536;
    __shared__ float tile[32][33];
    const int tx = threadIdx.x & 31, ty = threadIdx.x >> 5;
    #pragma unroll
    for (int p = 0; p < 4; ++p)
        tile[ty + p * 8][tx] = src[(size_t)(tk + ty + p * 8) * 256 + tn + tx];
    __syncthreads();
    #pragma unroll
    for (int p = 0; p < 4; ++p) {
        int n = tn + ty + p * 8;
        float v = tile[tx][ty + p * 8];
        size_t o = ((size_t)l * 1024 + z * 256 + n) * 256 + tk + tx;
        __hip_bfloat16 hi = __float2bfloat16(v);
        Whi[o] = hi;
        Wlo[o] = __float2bfloat16(v - __bfloat162float(hi));
    }
}

// W_init [128][256] -> Wt [256][128]
__global__ __launch_bounds__(256) void wt_init(const float* __restrict__ Wi,
        __hip_bfloat16* __restrict__ Whi, __hip_bfloat16* __restrict__ Wlo) {
    const int tk = (blockIdx.x & 3) * 32;
    const int tn = (blockIdx.x >> 2) * 32;
    __shared__ float tile[32][33];
    const int tx = threadIdx.x & 31, ty = threadIdx.x >> 5;
    #pragma unroll
    for (int p = 0; p < 4; ++p)
        tile[ty + p * 8][tx] = Wi[(size_t)(tk + ty + p * 8) * 256 + tn + tx];
    __syncthreads();
    #pragma unroll
    for (int p = 0; p < 4; ++p) {
        int n = tn + ty + p * 8;
        float v = tile[tx][ty + p * 8];
        size_t o = (size_t)n * 128 + tk + tx;
        __hip_bfloat16 hi = __float2bfloat16(v);
        Whi[o] = hi;
        Wlo[o] = __float2bfloat16(v - __bfloat162float(hi));
    }
}

__global__ __launch_bounds__(256) void bias_cat(const float* __restrict__ bq,
        const float* __restrict__ bk, const float* __restrict__ bv,
        const float* __restrict__ bs, float* __restrict__ bcat) {
    int l = blockIdx.x >> 2, z = blockIdx.x & 3;
    const float* b = (z == 0 ? bq : z == 1 ? bk : z == 2 ? bv : bs) + (size_t)l * 256;
    bcat[(size_t)l * 1024 + z * 256 + threadIdx.x] = b[threadIdx.x];
}

__global__ void conv_hi_lo(const float* __restrict__ src, int n,
                           __hip_bfloat16* __restrict__ hi, __hip_bfloat16* __restrict__ lo) {
    int i = blockIdx.x * blockDim.x + threadIdx.x;
    if (i < n) {
        float v = src[i];
        __hip_bfloat16 h = __float2bfloat16(v);
        hi[i] = h;
        lo[i] = __float2bfloat16(v - __bfloat162float(h));
    }
}

// ---------------- split-precision bf16 MFMA GEMM ----------------
// C[M x Ncols] = (Ahi+Alo)[M x K] @ (Bhi+Blo)^T [Ncols x K] + bias
// 128x128 tile, BK=32, 256 threads (2x2 waves of 64x64), m97-style staging.
// WRITE_MODE 0: fp32 C (ldc). WRITE_MODE 1: bf16 hi/lo pair (ld 256).
template <int WRITE_MODE>
__global__ __launch_bounds__(256) void gemm_mfma(
        const __hip_bfloat16* __restrict__ Ahi, const __hip_bfloat16* __restrict__ Alo,
        const __hip_bfloat16* __restrict__ Bhi, const __hip_bfloat16* __restrict__ Blo,
        const float* __restrict__ bias, int M, int K,
        float* __restrict__ C, int ldc,
        __hip_bfloat16* __restrict__ Chi, __hip_bfloat16* __restrict__ Clo) {
    const int t = threadIdx.x;
    const int lane = t & 63, wave = t >> 6;
    const int row0 = blockIdx.y * 128;
    const int col0 = blockIdx.x * 128;

    __shared__ __align__(16) __hip_bfloat16 smem[4 * 4096];
    __hip_bfloat16* sAhi = smem;
    __hip_bfloat16* sAlo = smem + 4096;
    __hip_bfloat16* sBhi = smem + 8192;
    __hip_bfloat16* sBlo = smem + 12288;

    // staging: 512 chunks of 16B per array; thread handles ch0, ch1
    const int ch0 = wave * 64 + lane;
    const int ch1 = ch0 + 256;
    const int rA0 = ch0 >> 2, cA0 = (ch0 & 3) ^ ((rA0 >> 1) & 3);
    const int rA1 = ch1 >> 2, cA1 = (ch1 & 3) ^ ((rA1 >> 1) & 3);
    const size_t gOff0 = (size_t)rA0 * K + cA0 * 8;   // element offset within tile row window
    const size_t gOff1 = (size_t)rA1 * K + cA1 * 8;
    const size_t gA0 = (size_t)row0 * K + gOff0, gA1 = (size_t)row0 * K + gOff1;
    const size_t gB0 = (size_t)col0 * K + gOff0, gB1 = (size_t)col0 * K + gOff1;

    // per-fragment LDS byte offsets (constant across K-steps)
    const int wr = wave >> 1, wc = wave & 1;
    int offA[4], offB[4];
    #pragma unroll
    for (int f = 0; f < 4; ++f) {
        int ra = wr * 64 + f * 16 + (lane & 15);
        offA[f] = ra * 64 + (((lane >> 4) ^ ((ra >> 1) & 3)) << 4);
        int rb = wc * 64 + f * 16 + (lane & 15);
        offB[f] = rb * 64 + (((lane >> 4) ^ ((rb >> 1) & 3)) << 4);
    }

    f32x4 acc[4][4] = {};

    const int nK = K >> 5;
    for (int ks = 0; ks < nK; ++ks) {
        const size_t ko = (size_t)ks * 32;
        gload_lds16((char*)sAhi + ch0 * 16, Ahi + gA0 + ko);
        gload_lds16((char*)sAhi + ch1 * 16, Ahi + gA1 + ko);
        gload_lds16((char*)sAlo + ch0 * 16, Alo + gA0 + ko);
        gload_lds16((char*)sAlo + ch1 * 16, Alo + gA1 + ko);
        gload_lds16((char*)sBhi + ch0 * 16, Bhi + gB0 + ko);
        gload_lds16((char*)sBhi + ch1 * 16, Bhi + gB1 + ko);
        gload_lds16((char*)sBlo + ch0 * 16, Blo + gB0 + ko);
        gload_lds16((char*)sBlo + ch1 * 16, Blo + gB1 + ko);
        __syncthreads();   // compiler drains vmcnt before barrier

        bf16x8 ah[4], al[4], bh[4], bl[4];
        #pragma unroll
        for (int f = 0; f < 4; ++f) {
            ah[f] = *(const bf16x8*)((const char*)sAhi + offA[f]);
            al[f] = *(const bf16x8*)((const char*)sAlo + offA[f]);
            bh[f] = *(const bf16x8*)((const char*)sBhi + offB[f]);
            bl[f] = *(const bf16x8*)((const char*)sBlo + offB[f]);
        }
        #pragma unroll
        for (int i = 0; i < 4; ++i)
            #pragma unroll
            for (int j = 0; j < 4; ++j) {
                acc[i][j] = __builtin_amdgcn_mfma_f32_16x16x32_bf16(al[i], bh[j], acc[i][j], 0, 0, 0);
                acc[i][j] = __builtin_amdgcn_mfma_f32_16x16x32_bf16(ah[i], bl[j], acc[i][j], 0, 0, 0);
                acc[i][j] = __builtin_amdgcn_mfma_f32_16x16x32_bf16(ah[i], bh[j], acc[i][j], 0, 0, 0);
            }
        __syncthreads();
    }

    // epilogue: C/D frag layout col=lane&15, row=(lane>>4)*4+reg  [m89-verified]
    const int rb = row0 + wr * 64;
    const int cb = col0 + wc * 64;
    #pragma unroll
    for (int i = 0; i < 4; ++i) {
        #pragma unroll
        for (int j = 0; j < 4; ++j) {
            const int c = cb + j * 16 + (lane & 15);
            const float bz = bias[c];
            #pragma unroll
            for (int rg = 0; rg < 4; ++rg) {
                const int r = rb + i * 16 + (lane >> 4) * 4 + rg;
                if (r < M) {
                    const float v = acc[i][j][rg] + bz;
                    if (WRITE_MODE == 0) {
                        C[(size_t)r * ldc + c] = v;
                    } else {
                        __hip_bfloat16 hi = __float2bfloat16(v);
                        Chi[(size_t)r * 256 + c] = hi;
                        Clo[(size_t)r * 256 + c] = __float2bfloat16(v - __bfloat162float(hi));
                    }
                }
            }
        }
    }
}

// ---------------- fused per-node attention + beta gate + LN + ReLU ----------------
__global__ __launch_bounds__(256) void node_attn_kernel(
        const float* __restrict__ qkvs, const int* __restrict__ offsets,
        const int* __restrict__ esrc, const float* __restrict__ Wbeta,
        const float* __restrict__ ln_g, const float* __restrict__ ln_b,
        float* __restrict__ h_out,
        __hip_bfloat16* __restrict__ h_hi, __hip_bfloat16* __restrict__ h_lo) {
    const int n = blockIdx.x;
    const int t = threadIdx.x;
    __shared__ int s_src[256];
    __shared__ float red[8];
    __shared__ float s_beta;

    const float q = qkvs[(size_t)n * 1024 + t];

    float m = -1e30f, ssum = 0.f, acc = 0.f;
    const int rs = offsets[n], re = offsets[n + 1];

    for (int base = rs; base < re; base += 256) {
        int cnt = min(re - base, 256);
        if (t < cnt) s_src[t] = esrc[base + t];
        __syncthreads();
        for (int j = 0; j < cnt; ++j) {
            const int sidx = s_src[j];
            const float* row = qkvs + (size_t)sidx * 1024;
            float p = q * row[256 + t];
            #pragma unroll
            for (int o = 16; o >= 1; o >>= 1) p += __shfl_xor(p, o, 32);
            float alpha = p * SCALE_ATT;
            float vv = row[512 + t];
            float mnew = fmaxf(m, alpha);
            float scale = __expf(m - mnew);
            float e = __expf(alpha - mnew);
            ssum = ssum * scale + e;
            acc  = acc  * scale + e * vv;
            m = mnew;
        }
        __syncthreads();
    }

    const float out = acc / (ssum + 1e-16f);
    const float xr  = qkvs[(size_t)n * 1024 + 768 + t];

    float bl = out * (Wbeta[t] + Wbeta[512 + t]) + xr * (Wbeta[256 + t] - Wbeta[512 + t]);
    #pragma unroll
    for (int o = 32; o >= 1; o >>= 1) bl += __shfl_xor(bl, o, 64);
    const int wave = t >> 6;
    if ((t & 63) == 0) red[wave] = bl;
    __syncthreads();
    if (t == 0) {
        float v = red[0] + red[1] + red[2] + red[3];
        s_beta = 1.f / (1.f + __expf(-v));
    }
    __syncthreads();
    const float beta = s_beta;
    const float hn = beta * xr + (1.f - beta) * out;

    float r1 = hn;
    #pragma unroll
    for (int o = 32; o >= 1; o >>= 1) r1 += __shfl_xor(r1, o, 64);
    if ((t & 63) == 0) red[4 + wave] = r1;
    __syncthreads();
    const float mu = (red[4] + red[5] + red[6] + red[7]) * (1.f / 256.f);
    const float d = hn - mu;
    float r2 = d * d;
    #pragma unroll
    for (int o = 32; o >= 1; o >>= 1) r2 += __shfl_xor(r2, o, 64);
    if ((t & 63) == 0) red[wave] = r2;
    __syncthreads();
    const float var = (red[0] + red[1] + red[2] + red[3]) * (1.f / 256.f);

    float y = d * rsqrtf(var + 1e-5f) * ln_g[t] + ln_b[t];
    y = fmaxf(y, 0.f);
    h_out[(size_t)n * 256 + t] = y;
    __hip_bfloat16 hi = __float2bfloat16(y);
    h_hi[(size_t)n * 256 + t] = hi;
    h_lo[(size_t)n * 256 + t] = __float2bfloat16(y - __bfloat162float(hi));
}

// ---------------- mean pool (batch sorted) ----------------
__global__ __launch_bounds__(256) void pool_kernel(const float* __restrict__ h,
                                                   const int* __restrict__ batch, int Nn,
                                                   float* __restrict__ sums,
                                                   float* __restrict__ cnt) {
    const int start = blockIdx.x * 256;
    const int end = min(start + 256, Nn);
    if (start >= end) return;
    const int t = threadIdx.x;
    int cur = batch[start];
    float run = 0.f;
    int c = 0;
    for (int n = start; n < end; ++n) {
        int g = batch[n];
        if (g != cur) {
            atomicAdd(&sums[(size_t)cur * 256 + t], run);
            if (t == 0) atomicAdd(&cnt[cur], (float)c);
            run = 0.f; c = 0; cur = g;
        }
        run += h[(size_t)n * 256 + t];
        ++c;
    }
    atomicAdd(&sums[(size_t)cur * 256 + t], run);
    if (t == 0) atomicAdd(&cnt[cur], (float)c);
}

__global__ __launch_bounds__(128) void final_kernel(const float* __restrict__ sums,
                                                    const float* __restrict__ cnt,
                                                    const float* __restrict__ Wf,
                                                    const float* __restrict__ bf,
                                                    float* __restrict__ out) {
    const int g = blockIdx.x;
    const int t = threadIdx.x;
    __shared__ float p[256];
    const float c = fmaxf(cnt[g], 1.f);
    for (int i = t; i < 256; i += 128) p[i] = sums[(size_t)g * 256 + i] / c;
    __syncthreads();
    float acc = bf[t];
    #pragma unroll 4
    for (int k = 0; k < 256; ++k) acc += p[k] * Wf[k * 128 + t];
    out[(size_t)g * 128 + t] = acc;
}

// ---------------- launcher ----------------
extern "C" void kernel_launch(void* const* d_in, const int* in_sizes, int n_in,
                              void* d_out, int out_size, void* d_ws, size_t ws_size,
                              hipStream_t stream) {
    const float* x       = (const float*)d_in[0];
    const int*   eidx    = (const int*)  d_in[1];
    const int*   batch   = (const int*)  d_in[2];
    const float* W_init  = (const float*)d_in[3];
    const float* b_init  = (const float*)d_in[4];
    const float* Wq      = (const float*)d_in[5];
    const float* bq      = (const float*)d_in[6];
    const float* Wk      = (const float*)d_in[7];
    const float* bk      = (const float*)d_in[8];
    const float* Wv      = (const float*)d_in[9];
    const float* bv      = (const float*)d_in[10];
    const float* Ws      = (const float*)d_in[11];
    const float* bs      = (const float*)d_in[12];
    const float* Wbeta   = (const float*)d_in[13];
    const float* ln_g    = (const float*)d_in[14];
    const float* ln_b    = (const float*)d_in[15];
    const float* W_final = (const float*)d_in[16];
    const float* b_final = (const float*)d_in[17];

    const int* e_src = eidx;
    const int* e_dst = eidx + E_EDGES;

    // workspace layout
    char* p = (char*)d_ws;
    auto alloc = [&](size_t bytes) {
        void* r = (void*)p;
        p += (bytes + 255) & ~(size_t)255;
        return r;
    };
    float* h      = (float*)alloc((size_t)M_PAD * 256 * 4);
    float* qkvs   = (float*)alloc((size_t)N_NODES * 1024 * 4);
    __hip_bfloat16* h_hi = (__hip_bfloat16*)alloc((size_t)M_PAD * 256 * 2);
    __hip_bfloat16* h_lo = (__hip_bfloat16*)alloc((size_t)M_PAD * 256 * 2);
    __hip_bfloat16* x_hi = (__hip_bfloat16*)alloc((size_t)M_PAD * 128 * 2);
    __hip_bfloat16* x_lo = (__hip_bfloat16*)alloc((size_t)M_PAD * 128 * 2);
    __hip_bfloat16* Wt_hi = (__hip_bfloat16*)alloc((size_t)LAYERS * 1024 * 256 * 2);
    __hip_bfloat16* Wt_lo = (__hip_bfloat16*)alloc((size_t)LAYERS * 1024 * 256 * 2);
    __hip_bfloat16* Wi_hi = (__hip_bfloat16*)alloc((size_t)256 * 128 * 2);
    __hip_bfloat16* Wi_lo = (__hip_bfloat16*)alloc((size_t)256 * 128 * 2);
    float* bcat   = (float*)alloc((size_t)LAYERS * 1024 * 4);
    int* counts   = (int*)alloc((size_t)N_NODES * 4);
    int* offsets  = (int*)alloc((size_t)(N_NODES + 1) * 4);
    int* cursor   = (int*)alloc((size_t)N_NODES * 4);
    int* esrc     = (int*)alloc((size_t)E_EDGES * 4);
    float* sums   = (float*)alloc((size_t)G_GRAPHS * 256 * 4);
    float* cnt    = (float*)alloc((size_t)G_GRAPHS * 4);

    hipMemsetAsync(counts, 0, sizeof(int) * N_NODES, stream);
    hipMemsetAsync(cursor, 0, sizeof(int) * N_NODES, stream);
    hipMemsetAsync(sums, 0, sizeof(float) * G_GRAPHS * 256, stream);
    hipMemsetAsync(cnt, 0, sizeof(float) * G_GRAPHS, stream);

    // CSR by dst
    count_kernel<<<(E_EDGES + 255) / 256, 256, 0, stream>>>(e_dst, E_EDGES, counts);
    scan_kernel<<<1, 1024, 0, stream>>>(counts, offsets, N_NODES);
    scatter_kernel<<<(E_EDGES + 255) / 256, 256, 0, stream>>>(e_src, e_dst, E_EDGES,
                                                              offsets, cursor, esrc);

    // weight prep
    wt_layers<<<dim3(64, 4, LAYERS), 256, 0, stream>>>(Wq, Wk, Wv, Ws, Wt_hi, Wt_lo);
    wt_init<<<32, 256, 0, stream>>>(W_init, Wi_hi, Wi_lo);
    bias_cat<<<LAYERS * 4, 256, 0, stream>>>(bq, bk, bv, bs, bcat);
    conv_hi_lo<<<(N_NODES * 128 + 255) / 256, 256, 0, stream>>>(x, N_NODES * 128, x_hi, x_lo);

    const int rowTiles = M_PAD / 128;   // 157

    // h0 = x @ W_init + b_init  -> bf16 hi/lo directly
    gemm_mfma<1><<<dim3(2, rowTiles), 256, 0, stream>>>(
        x_hi, x_lo, Wi_hi, Wi_lo, b_init, N_NODES, 128,
        nullptr, 0, h_hi, h_lo);

    for (int l = 0; l < LAYERS; ++l) {
        gemm_mfma<0><<<dim3(8, rowTiles), 256, 0, stream>>>(
            h_hi, h_lo,
            Wt_hi + (size_t)l * 1024 * 256, Wt_lo + (size_t)l * 1024 * 256,
            bcat + (size_t)l * 1024, N_NODES, 256,
            qkvs, 1024, nullptr, nullptr);

        node_attn_kernel<<<N_NODES, 256, 0, stream>>>(
            qkvs, offsets, esrc,
            Wbeta + (size_t)l * 768,
            ln_g + (size_t)l * 256, ln_b + (size_t)l * 256,
            h, h_hi, h_lo);
    }

    pool_kernel<<<(N_NODES + 255) / 256, 256, 0, stream>>>(h, batch, N_NODES, sums, cnt);
    final_kernel<<<G_GRAPHS, 128, 0, stream>>>(sums, cnt, W_final, b_final, (float*)d_out);
}

// Round 3
// 1508.577 us; speedup vs baseline: 1.5809x; 1.1782x over previous
//
#include <hip/hip_runtime.h>
#include <hip/hip_bf16.h>
#include <math.h>

// ---------------- problem constants ----------------
constexpr int N_NODES  = 20000;
constexpr int M_PAD    = 20096;   // 157 * 128 row tiles
constexpr int E_EDGES  = 320000;
constexpr int G_GRAPHS = 64;
constexpr int F_IN     = 128;
constexpr int H_DIM    = 256;
constexpr int LAYERS   = 8;
constexpr float SCALE_ATT = 0.17677669529663687f; // 1/sqrt(32)

typedef __attribute__((ext_vector_type(8))) short bf16x8;
typedef __attribute__((ext_vector_type(4))) float f32x4;
typedef unsigned int u32;

__device__ static inline void gload_lds16(void* lds, const void* g) {
    __builtin_amdgcn_global_load_lds((const __attribute__((address_space(1))) u32*)g,
                                     (__attribute__((address_space(3))) u32*)lds, 16, 0, 0);
}

// ---------------- CSR build ----------------
__global__ void count_kernel(const int* __restrict__ dst, int E, int* __restrict__ counts) {
    int i = blockIdx.x * blockDim.x + threadIdx.x;
    if (i < E) atomicAdd(&counts[dst[i]], 1);
}

__global__ __launch_bounds__(1024) void scan_kernel(const int* __restrict__ counts,
                                                    int* __restrict__ offsets, int n) {
    __shared__ int buf[1024];
    __shared__ int carry;
    const int tid = threadIdx.x;
    if (tid == 0) { carry = 0; offsets[0] = 0; }
    __syncthreads();
    for (int base = 0; base < n; base += 1024) {
        int i = base + tid;
        int v = (i < n) ? counts[i] : 0;
        buf[tid] = v;
        __syncthreads();
        #pragma unroll
        for (int off = 1; off < 1024; off <<= 1) {
            int x = (tid >= off) ? buf[tid - off] : 0;
            __syncthreads();
            buf[tid] += x;
            __syncthreads();
        }
        if (i < n) offsets[i + 1] = carry + buf[tid];
        __syncthreads();
        if (tid == 0) carry += buf[1023];
        __syncthreads();
    }
}

__global__ void scatter_kernel(const int* __restrict__ src, const int* __restrict__ dst, int E,
                               const int* __restrict__ offsets, int* __restrict__ cursor,
                               int* __restrict__ esrc) {
    int i = blockIdx.x * blockDim.x + threadIdx.x;
    if (i < E) {
        int d = dst[i];
        int pos = atomicAdd(&cursor[d], 1);
        esrc[offsets[d] + pos] = src[i];
    }
}

// ---------------- weight transpose + hi/lo bf16 split ----------------
__global__ __launch_bounds__(256) void wt_layers(
        const float* __restrict__ Wq, const float* __restrict__ Wk,
        const float* __restrict__ Wv, const float* __restrict__ Ws,
        __hip_bfloat16* __restrict__ Whi, __hip_bfloat16* __restrict__ Wlo) {
    const int l = blockIdx.z, z = blockIdx.y;
    const int tk = (blockIdx.x & 7) * 32;
    const int tn = (blockIdx.x >> 3) * 32;
    const float* src = (z == 0 ? Wq : z == 1 ? Wk : z == 2 ? Wv : Ws) + (size_t)l * 65536;
    __shared__ float tile[32][33];
    const int tx = threadIdx.x & 31, ty = threadIdx.x >> 5;
    #pragma unroll
    for (int p = 0; p < 4; ++p)
        tile[ty + p * 8][tx] = src[(size_t)(tk + ty + p * 8) * 256 + tn + tx];
    __syncthreads();
    #pragma unroll
    for (int p = 0; p < 4; ++p) {
        int n = tn + ty + p * 8;
        float v = tile[tx][ty + p * 8];
        size_t o = ((size_t)l * 1024 + z * 256 + n) * 256 + tk + tx;
        __hip_bfloat16 hi = __float2bfloat16(v);
        Whi[o] = hi;
        Wlo[o] = __float2bfloat16(v - __bfloat162float(hi));
    }
}

__global__ __launch_bounds__(256) void wt_init(const float* __restrict__ Wi,
        __hip_bfloat16* __restrict__ Whi, __hip_bfloat16* __restrict__ Wlo) {
    const int tk = (blockIdx.x & 3) * 32;
    const int tn = (blockIdx.x >> 2) * 32;
    __shared__ float tile[32][33];
    const int tx = threadIdx.x & 31, ty = threadIdx.x >> 5;
    #pragma unroll
    for (int p = 0; p < 4; ++p)
        tile[ty + p * 8][tx] = Wi[(size_t)(tk + ty + p * 8) * 256 + tn + tx];
    __syncthreads();
    #pragma unroll
    for (int p = 0; p < 4; ++p) {
        int n = tn + ty + p * 8;
        float v = tile[tx][ty + p * 8];
        size_t o = (size_t)n * 128 + tk + tx;
        __hip_bfloat16 hi = __float2bfloat16(v);
        Whi[o] = hi;
        Wlo[o] = __float2bfloat16(v - __bfloat162float(hi));
    }
}

__global__ __launch_bounds__(256) void bias_cat(const float* __restrict__ bq,
        const float* __restrict__ bk, const float* __restrict__ bv,
        const float* __restrict__ bs, float* __restrict__ bcat) {
    int l = blockIdx.x >> 2, z = blockIdx.x & 3;
    const float* b = (z == 0 ? bq : z == 1 ? bk : z == 2 ? bv : bs) + (size_t)l * 256;
    bcat[(size_t)l * 1024 + z * 256 + threadIdx.x] = b[threadIdx.x];
}

__global__ void conv_hi_lo(const float* __restrict__ src, int n,
                           __hip_bfloat16* __restrict__ hi, __hip_bfloat16* __restrict__ lo) {
    int i = blockIdx.x * blockDim.x + threadIdx.x;
    if (i < n) {
        float v = src[i];
        __hip_bfloat16 h = __float2bfloat16(v);
        hi[i] = h;
        lo[i] = __float2bfloat16(v - __bfloat162float(h));
    }
}

// ---------------- split-precision bf16 MFMA GEMM ----------------
template <int WRITE_MODE>
__global__ __launch_bounds__(256) void gemm_mfma(
        const __hip_bfloat16* __restrict__ Ahi, const __hip_bfloat16* __restrict__ Alo,
        const __hip_bfloat16* __restrict__ Bhi, const __hip_bfloat16* __restrict__ Blo,
        const float* __restrict__ bias, int M, int K,
        float* __restrict__ C, int ldc,
        __hip_bfloat16* __restrict__ Chi, __hip_bfloat16* __restrict__ Clo) {
    const int t = threadIdx.x;
    const int lane = t & 63, wave = t >> 6;
    const int row0 = blockIdx.y * 128;
    const int col0 = blockIdx.x * 128;

    __shared__ __align__(16) __hip_bfloat16 smem[4 * 4096];
    __hip_bfloat16* sAhi = smem;
    __hip_bfloat16* sAlo = smem + 4096;
    __hip_bfloat16* sBhi = smem + 8192;
    __hip_bfloat16* sBlo = smem + 12288;

    const int ch0 = wave * 64 + lane;
    const int ch1 = ch0 + 256;
    const int rA0 = ch0 >> 2, cA0 = (ch0 & 3) ^ ((rA0 >> 1) & 3);
    const int rA1 = ch1 >> 2, cA1 = (ch1 & 3) ^ ((rA1 >> 1) & 3);
    const size_t gOff0 = (size_t)rA0 * K + cA0 * 8;
    const size_t gOff1 = (size_t)rA1 * K + cA1 * 8;
    const size_t gA0 = (size_t)row0 * K + gOff0, gA1 = (size_t)row0 * K + gOff1;
    const size_t gB0 = (size_t)col0 * K + gOff0, gB1 = (size_t)col0 * K + gOff1;

    const int wr = wave >> 1, wc = wave & 1;
    int offA[4], offB[4];
    #pragma unroll
    for (int f = 0; f < 4; ++f) {
        int ra = wr * 64 + f * 16 + (lane & 15);
        offA[f] = ra * 64 + (((lane >> 4) ^ ((ra >> 1) & 3)) << 4);
        int rb = wc * 64 + f * 16 + (lane & 15);
        offB[f] = rb * 64 + (((lane >> 4) ^ ((rb >> 1) & 3)) << 4);
    }

    f32x4 acc[4][4] = {};

    const int nK = K >> 5;
    for (int ks = 0; ks < nK; ++ks) {
        const size_t ko = (size_t)ks * 32;
        gload_lds16((char*)sAhi + ch0 * 16, Ahi + gA0 + ko);
        gload_lds16((char*)sAhi + ch1 * 16, Ahi + gA1 + ko);
        gload_lds16((char*)sAlo + ch0 * 16, Alo + gA0 + ko);
        gload_lds16((char*)sAlo + ch1 * 16, Alo + gA1 + ko);
        gload_lds16((char*)sBhi + ch0 * 16, Bhi + gB0 + ko);
        gload_lds16((char*)sBhi + ch1 * 16, Bhi + gB1 + ko);
        gload_lds16((char*)sBlo + ch0 * 16, Blo + gB0 + ko);
        gload_lds16((char*)sBlo + ch1 * 16, Blo + gB1 + ko);
        __syncthreads();

        bf16x8 ah[4], al[4], bh[4], bl[4];
        #pragma unroll
        for (int f = 0; f < 4; ++f) {
            ah[f] = *(const bf16x8*)((const char*)sAhi + offA[f]);
            al[f] = *(const bf16x8*)((const char*)sAlo + offA[f]);
            bh[f] = *(const bf16x8*)((const char*)sBhi + offB[f]);
            bl[f] = *(const bf16x8*)((const char*)sBlo + offB[f]);
        }
        #pragma unroll
        for (int i = 0; i < 4; ++i)
            #pragma unroll
            for (int j = 0; j < 4; ++j) {
                acc[i][j] = __builtin_amdgcn_mfma_f32_16x16x32_bf16(al[i], bh[j], acc[i][j], 0, 0, 0);
                acc[i][j] = __builtin_amdgcn_mfma_f32_16x16x32_bf16(ah[i], bl[j], acc[i][j], 0, 0, 0);
                acc[i][j] = __builtin_amdgcn_mfma_f32_16x16x32_bf16(ah[i], bh[j], acc[i][j], 0, 0, 0);
            }
        __syncthreads();
    }

    const int rb = row0 + wr * 64;
    const int cb = col0 + wc * 64;
    #pragma unroll
    for (int i = 0; i < 4; ++i) {
        #pragma unroll
        for (int j = 0; j < 4; ++j) {
            const int c = cb + j * 16 + (lane & 15);
            const float bz = bias[c];
            #pragma unroll
            for (int rg = 0; rg < 4; ++rg) {
                const int r = rb + i * 16 + (lane >> 4) * 4 + rg;
                if (r < M) {
                    const float v = acc[i][j][rg] + bz;
                    if (WRITE_MODE == 0) {
                        C[(size_t)r * ldc + c] = v;
                    } else {
                        __hip_bfloat16 hi = __float2bfloat16(v);
                        Chi[(size_t)r * 256 + c] = hi;
                        Clo[(size_t)r * 256 + c] = __float2bfloat16(v - __bfloat162float(hi));
                    }
                }
            }
        }
    }
}

// ---------------- fused per-node attention + beta gate + LN + ReLU ----------------
// One edge per WAVE (lane holds 4 channels); 4 edges in flight per block;
// flash-style merge of the 4 per-wave online-softmax partials.
__global__ __launch_bounds__(256) void node_attn_kernel(
        const float* __restrict__ qkvs, const int* __restrict__ offsets,
        const int* __restrict__ esrc, const float* __restrict__ Wbeta,
        const float* __restrict__ ln_g, const float* __restrict__ ln_b,
        float* __restrict__ h_out,
        __hip_bfloat16* __restrict__ h_hi, __hip_bfloat16* __restrict__ h_lo) {
    const int n = blockIdx.x;
    const int t = threadIdx.x;
    const int lane = t & 63, wave = t >> 6;
    __shared__ int s_src[256];
    __shared__ float s_acc[4][256];
    __shared__ float s_m[4][8];
    __shared__ float s_s[4][8];
    __shared__ float red[8];
    __shared__ float s_beta;

    // lane holds channels 4*lane .. 4*lane+3 (all within head lane>>3)
    float4 q4 = *reinterpret_cast<const float4*>(qkvs + (size_t)n * 1024 + lane * 4);
    q4.x *= SCALE_ATT; q4.y *= SCALE_ATT; q4.z *= SCALE_ATT; q4.w *= SCALE_ATT;

    float m = -1e30f, ssum = 0.f;
    float4 acc = make_float4(0.f, 0.f, 0.f, 0.f);
    const int rs = offsets[n], re = offsets[n + 1];

    for (int base = rs; base < re; base += 256) {
        int cnt = min(re - base, 256);
        if (t < cnt) s_src[t] = esrc[base + t];
        __syncthreads();
        for (int j = wave; j < cnt; j += 4) {
            const int sidx = s_src[j];
            const float4* row = reinterpret_cast<const float4*>(qkvs + (size_t)sidx * 1024);
            const float4 kk = row[64 + lane];    // k at float-offset 256
            const float4 vv = row[128 + lane];   // v at float-offset 512
            float p = q4.x * kk.x + q4.y * kk.y + q4.z * kk.z + q4.w * kk.w;
            p += __shfl_xor(p, 1, 8);
            p += __shfl_xor(p, 2, 8);
            p += __shfl_xor(p, 4, 8);            // alpha for head lane>>3
            const float mnew = fmaxf(m, p);
            const float scale = __expf(m - mnew);
            const float e = __expf(p - mnew);
            ssum = ssum * scale + e;
            acc.x = acc.x * scale + e * vv.x;
            acc.y = acc.y * scale + e * vv.y;
            acc.z = acc.z * scale + e * vv.z;
            acc.w = acc.w * scale + e * vv.w;
            m = mnew;
        }
        __syncthreads();
    }

    // merge 4 per-wave partials
    *reinterpret_cast<float4*>(&s_acc[wave][lane * 4]) = acc;
    if ((lane & 7) == 0) { s_m[wave][lane >> 3] = m; s_s[wave][lane >> 3] = ssum; }
    __syncthreads();

    const int hd = t >> 5;
    const float m0 = s_m[0][hd], m1 = s_m[1][hd], m2 = s_m[2][hd], m3 = s_m[3][hd];
    const float mx = fmaxf(fmaxf(m0, m1), fmaxf(m2, m3));
    const float c0 = __expf(m0 - mx), c1 = __expf(m1 - mx);
    const float c2 = __expf(m2 - mx), c3 = __expf(m3 - mx);
    const float den = s_s[0][hd] * c0 + s_s[1][hd] * c1 + s_s[2][hd] * c2 + s_s[3][hd] * c3;
    const float out = (s_acc[0][t] * c0 + s_acc[1][t] * c1 + s_acc[2][t] * c2 + s_acc[3][t] * c3)
                      / (den + 1e-16f);

    const float xr = qkvs[(size_t)n * 1024 + 768 + t];

    float bl = out * (Wbeta[t] + Wbeta[512 + t]) + xr * (Wbeta[256 + t] - Wbeta[512 + t]);
    #pragma unroll
    for (int o = 32; o >= 1; o >>= 1) bl += __shfl_xor(bl, o, 64);
    if ((t & 63) == 0) red[wave] = bl;
    __syncthreads();
    if (t == 0) {
        float v = red[0] + red[1] + red[2] + red[3];
        s_beta = 1.f / (1.f + __expf(-v));
    }
    __syncthreads();
    const float beta = s_beta;
    const float hn = beta * xr + (1.f - beta) * out;

    float r1 = hn;
    #pragma unroll
    for (int o = 32; o >= 1; o >>= 1) r1 += __shfl_xor(r1, o, 64);
    if ((t & 63) == 0) red[4 + wave] = r1;
    __syncthreads();
    const float mu = (red[4] + red[5] + red[6] + red[7]) * (1.f / 256.f);
    const float d = hn - mu;
    float r2 = d * d;
    #pragma unroll
    for (int o = 32; o >= 1; o >>= 1) r2 += __shfl_xor(r2, o, 64);
    if ((t & 63) == 0) red[wave] = r2;
    __syncthreads();
    const float var = (red[0] + red[1] + red[2] + red[3]) * (1.f / 256.f);

    float y = d * rsqrtf(var + 1e-5f) * ln_g[t] + ln_b[t];
    y = fmaxf(y, 0.f);
    h_out[(size_t)n * 256 + t] = y;
    __hip_bfloat16 hi = __float2bfloat16(y);
    h_hi[(size_t)n * 256 + t] = hi;
    h_lo[(size_t)n * 256 + t] = __float2bfloat16(y - __bfloat162float(hi));
}

// ---------------- mean pool (batch sorted) ----------------
__global__ __launch_bounds__(256) void pool_kernel(const float* __restrict__ h,
                                                   const int* __restrict__ batch, int Nn,
                                                   float* __restrict__ sums,
                                                   float* __restrict__ cnt) {
    const int start = blockIdx.x * 256;
    const int end = min(start + 256, Nn);
    if (start >= end) return;
    const int t = threadIdx.x;
    int cur = batch[start];
    float run = 0.f;
    int c = 0;
    for (int n = start; n < end; ++n) {
        int g = batch[n];
        if (g != cur) {
            atomicAdd(&sums[(size_t)cur * 256 + t], run);
            if (t == 0) atomicAdd(&cnt[cur], (float)c);
            run = 0.f; c = 0; cur = g;
        }
        run += h[(size_t)n * 256 + t];
        ++c;
    }
    atomicAdd(&sums[(size_t)cur * 256 + t], run);
    if (t == 0) atomicAdd(&cnt[cur], (float)c);
}

__global__ __launch_bounds__(128) void final_kernel(const float* __restrict__ sums,
                                                    const float* __restrict__ cnt,
                                                    const float* __restrict__ Wf,
                                                    const float* __restrict__ bf,
                                                    float* __restrict__ out) {
    const int g = blockIdx.x;
    const int t = threadIdx.x;
    __shared__ float p[256];
    const float c = fmaxf(cnt[g], 1.f);
    for (int i = t; i < 256; i += 128) p[i] = sums[(size_t)g * 256 + i] / c;
    __syncthreads();
    float acc = bf[t];
    #pragma unroll 4
    for (int k = 0; k < 256; ++k) acc += p[k] * Wf[k * 128 + t];
    out[(size_t)g * 128 + t] = acc;
}

// ---------------- launcher ----------------
extern "C" void kernel_launch(void* const* d_in, const int* in_sizes, int n_in,
                              void* d_out, int out_size, void* d_ws, size_t ws_size,
                              hipStream_t stream) {
    const float* x       = (const float*)d_in[0];
    const int*   eidx    = (const int*)  d_in[1];
    const int*   batch   = (const int*)  d_in[2];
    const float* W_init  = (const float*)d_in[3];
    const float* b_init  = (const float*)d_in[4];
    const float* Wq      = (const float*)d_in[5];
    const float* bq      = (const float*)d_in[6];
    const float* Wk      = (const float*)d_in[7];
    const float* bk      = (const float*)d_in[8];
    const float* Wv      = (const float*)d_in[9];
    const float* bv      = (const float*)d_in[10];
    const float* Ws      = (const float*)d_in[11];
    const float* bs      = (const float*)d_in[12];
    const float* Wbeta   = (const float*)d_in[13];
    const float* ln_g    = (const float*)d_in[14];
    const float* ln_b    = (const float*)d_in[15];
    const float* W_final = (const float*)d_in[16];
    const float* b_final = (const float*)d_in[17];

    const int* e_src = eidx;
    const int* e_dst = eidx + E_EDGES;

    char* p = (char*)d_ws;
    auto alloc = [&](size_t bytes) {
        void* r = (void*)p;
        p += (bytes + 255) & ~(size_t)255;
        return r;
    };
    float* h      = (float*)alloc((size_t)M_PAD * 256 * 4);
    float* qkvs   = (float*)alloc((size_t)N_NODES * 1024 * 4);
    __hip_bfloat16* h_hi = (__hip_bfloat16*)alloc((size_t)M_PAD * 256 * 2);
    __hip_bfloat16* h_lo = (__hip_bfloat16*)alloc((size_t)M_PAD * 256 * 2);
    __hip_bfloat16* x_hi = (__hip_bfloat16*)alloc((size_t)M_PAD * 128 * 2);
    __hip_bfloat16* x_lo = (__hip_bfloat16*)alloc((size_t)M_PAD * 128 * 2);
    __hip_bfloat16* Wt_hi = (__hip_bfloat16*)alloc((size_t)LAYERS * 1024 * 256 * 2);
    __hip_bfloat16* Wt_lo = (__hip_bfloat16*)alloc((size_t)LAYERS * 1024 * 256 * 2);
    __hip_bfloat16* Wi_hi = (__hip_bfloat16*)alloc((size_t)256 * 128 * 2);
    __hip_bfloat16* Wi_lo = (__hip_bfloat16*)alloc((size_t)256 * 128 * 2);
    float* bcat   = (float*)alloc((size_t)LAYERS * 1024 * 4);
    int* counts   = (int*)alloc((size_t)N_NODES * 4);
    int* offsets  = (int*)alloc((size_t)(N_NODES + 1) * 4);
    int* cursor   = (int*)alloc((size_t)N_NODES * 4);
    int* esrc     = (int*)alloc((size_t)E_EDGES * 4);
    float* sums   = (float*)alloc((size_t)G_GRAPHS * 256 * 4);
    float* cnt    = (float*)alloc((size_t)G_GRAPHS * 4);

    hipMemsetAsync(counts, 0, sizeof(int) * N_NODES, stream);
    hipMemsetAsync(cursor, 0, sizeof(int) * N_NODES, stream);
    hipMemsetAsync(sums, 0, sizeof(float) * G_GRAPHS * 256, stream);
    hipMemsetAsync(cnt, 0, sizeof(float) * G_GRAPHS, stream);

    count_kernel<<<(E_EDGES + 255) / 256, 256, 0, stream>>>(e_dst, E_EDGES, counts);
    scan_kernel<<<1, 1024, 0, stream>>>(counts, offsets, N_NODES);
    scatter_kernel<<<(E_EDGES + 255) / 256, 256, 0, stream>>>(e_src, e_dst, E_EDGES,
                                                              offsets, cursor, esrc);

    wt_layers<<<dim3(64, 4, LAYERS), 256, 0, stream>>>(Wq, Wk, Wv, Ws, Wt_hi, Wt_lo);
    wt_init<<<32, 256, 0, stream>>>(W_init, Wi_hi, Wi_lo);
    bias_cat<<<LAYERS * 4, 256, 0, stream>>>(bq, bk, bv, bs, bcat);
    conv_hi_lo<<<(N_NODES * 128 + 255) / 256, 256, 0, stream>>>(x, N_NODES * 128, x_hi, x_lo);

    const int rowTiles = M_PAD / 128;   // 157

    gemm_mfma<1><<<dim3(2, rowTiles), 256, 0, stream>>>(
        x_hi, x_lo, Wi_hi, Wi_lo, b_init, N_NODES, 128,
        nullptr, 0, h_hi, h_lo);

    for (int l = 0; l < LAYERS; ++l) {
        gemm_mfma<0><<<dim3(8, rowTiles), 256, 0, stream>>>(
            h_hi, h_lo,
            Wt_hi + (size_t)l * 1024 * 256, Wt_lo + (size_t)l * 1024 * 256,
            bcat + (size_t)l * 1024, N_NODES, 256,
            qkvs, 1024, nullptr, nullptr);

        node_attn_kernel<<<N_NODES, 256, 0, stream>>>(
            qkvs, offsets, esrc,
            Wbeta + (size_t)l * 768,
            ln_g + (size_t)l * 256, ln_b + (size_t)l * 256,
            h, h_hi, h_lo);
    }

    pool_kernel<<<(N_NODES + 255) / 256, 256, 0, stream>>>(h, batch, N_NODES, sums, cnt);
    final_kernel<<<G_GRAPHS, 128, 0, stream>>>(sums, cnt, W_final, b_final, (float*)d_out);
}